// Round 1
// baseline (183.606 us; speedup 1.0000x reference)
//
#include <hip/hip_runtime.h>
#include <hip/hip_bf16.h>

// Problem constants
#define N_TOK 8192
#define INL   512
#define OUTL  512
#define NE    8
#define NI    16
#define EOFF  (OUTL * INL)   // elems per expert in wt

typedef unsigned short ushort_t;
typedef unsigned int   uint_t;
typedef short  short8  __attribute__((ext_vector_type(8)));
typedef float  floatx4 __attribute__((ext_vector_type(4)));

// ---------------- workspace layout (bytes) ----------------
#define WS_CNT    0u         // int[16] @ stride 16 ints (64B): [slot*8+e]
#define WS_GAM    2048u      // float[8]   : gam[e]
#define WS_RGAM   2080u      // float[8]   : router_gamma[e]
#define WS_BET    2112u      // float[4096]: bet_eff[e][d] = bet + gam*b
#define WS_SELE   18496u     // int[8192]  : e0 | e1<<8
#define WS_SELW   51264u     // float4[8192]: {rw0*gam0, rw1*gam1, rw0, rw1}
#define WS_WT     182336u    // ushort[8*512*512] : W^T bf16 [e][d][l]
#define WS_LIST   4380672u   // int[2*8*8192] : token lists per (slot, expert)
#define MAXT      136        // worst-case sum of ceil(cnt_e/64) + safety

__device__ __forceinline__ ushort_t f2bf(float f) {
    uint_t b = __float_as_uint(f);
    return (ushort_t)((b + 0x7FFFu + ((b >> 16) & 1u)) >> 16);   // RNE
}
__device__ __forceinline__ uint_t pkbf(float a, float b) {
    __hip_bfloat162 h = __float22bfloat162_rn(make_float2(a, b));  // v_cvt_pk_bf16_f32
    union { __hip_bfloat162 h2; uint_t u; } cv;
    cv.h2 = h;
    return cv.u;
}
// async global->LDS DMA, 16 B per lane; LDS dest = wave-uniform base + lane*16
__device__ __forceinline__ void dma16(const ushort_t* g, ushort_t* l) {
    __builtin_amdgcn_global_load_lds(
        (const __attribute__((address_space(1))) void*)g,
        (__attribute__((address_space(3))) void*)l,
        16, 0, 0);
}

// ================= K1: fused prep =================
// blocks [0,512):   Wt transpose/convert  (e = bx>>6; tile = bx&63)
// blocks [512,640): bet_eff               (e = b>>4; dBase = (b&15)*32)
// block  640:       stats -> wsGam, wsRgam; zero scatter counters
__global__ __launch_bounds__(256)
void k_prep(const float* __restrict__ ins,
            const float* __restrict__ expert_w,
            const float* __restrict__ expert_b,
            const float* __restrict__ gamma_w,
            const float* __restrict__ beta_w,
            const float* __restrict__ rmod_w,
            ushort_t* __restrict__ wt,
            float* __restrict__ wsBet,
            float* __restrict__ wsGam, float* __restrict__ wsRgam,
            int* __restrict__ wsCnt) {
    __shared__ __align__(16) char smem[17152];
    int bx = blockIdx.x;
    int tid = threadIdx.x;

    if (bx < 512) {
        float (*tile)[65] = (float(*)[65])smem;
        int e = bx >> 6, rem = bx & 63;
        int lt = (rem >> 3) * 64, dt = (rem & 7) * 64;
        int dIdx = tid & 63, lq = tid >> 6;
        for (int i = 0; i < 16; ++i) {
            int l = lq * 16 + i;
            tile[l][dIdx] = expert_w[(e * INL + lt + l) * OUTL + dt + dIdx];
        }
        __syncthreads();
        int lIdx = tid & 63, dq = tid >> 6;
        for (int i = 0; i < 16; ++i) {
            int d = dq * 16 + i;
            wt[(e * OUTL + dt + d) * INL + lt + lIdx] = f2bf(tile[lIdx][d]);
        }
        return;
    }

    if (bx < 640) {
        float* sS  = (float*)smem;          // [512]
        float* red = sS + 512;              // [256]
        float* gamS = red + 256;            // [1]
        int b2 = bx - 512;
        int e = b2 >> 4, dBase = (b2 & 15) * 32;
        for (int h = tid; h < INL; h += 256) {
            float a = 0.f;
            for (int n = 0; n < NI; ++n) a += ins[n * INL + h];
            sS[h] = a;
        }
        __syncthreads();
        if (tid < 64) {
            float g = 0.f;
            for (int j = 0; j < 8; ++j) g += sS[tid * 8 + j] * gamma_w[e * INL + tid * 8 + j];
            for (int off = 32; off >= 1; off >>= 1) g += __shfl_xor(g, off, 64);
            if (tid == 0) gamS[0] = g * (1.f / NI);
        }
        int doff = tid & 31, hq = tid >> 5;
        float a = 0.f;
        for (int j = 0; j < 64; ++j) {
            int h = hq * 64 + j;
            a += sS[h] * beta_w[(e * INL + h) * OUTL + dBase + doff];
        }
        red[tid] = a;
        __syncthreads();
        if (tid < 32) {
            float t = 0.f;
            for (int k = 0; k < 8; ++k) t += red[k * 32 + tid];
            int d = dBase + tid;
            wsBet[e * OUTL + d] = t * (1.f / NI) + gamS[0] * expert_b[e * OUTL + d];
        }
        return;
    }

    {   // stats
        if (tid < 16) wsCnt[tid * 16] = 0;   // zero scatter counters for k_route
        float* sS = (float*)smem;           // [512]
        float* pg = sS + 512;               // [64]
        float* pr = pg + 64;                // [64]
        for (int h = tid; h < INL; h += 256) {
            float a = 0.f;
            for (int n = 0; n < NI; ++n) a += ins[n * INL + h];
            sS[h] = a;
        }
        __syncthreads();
        if (tid < 64) {
            int e = tid & 7, qq = tid >> 3;
            float g = 0.f, r = 0.f;
            for (int j = 0; j < 64; ++j) {
                int h = qq * 64 + j;
                float sv = sS[h];
                g += sv * gamma_w[e * INL + h];
                r += sv * rmod_w[h * NE + e];
            }
            pg[tid] = g; pr[tid] = r;
        }
        __syncthreads();
        if (tid < NE) {
            float g = 0.f, r = 0.f;
            for (int qq = 0; qq < 8; ++qq) { g += pg[qq * 8 + tid]; r += pr[qq * 8 + tid]; }
            wsGam[tid]  = g * (1.f / NI);
            wsRgam[tid] = r * (1.f / NI);
        }
    }
}

// ================= K2: router (fp32 logits) + expert scatter =================
__global__ void k_route(const float* __restrict__ x,
                        const float* __restrict__ gate_w,
                        const float* __restrict__ wsGam,
                        const float* __restrict__ wsRgam,
                        int* __restrict__ selE, float4* __restrict__ selW,
                        int* __restrict__ wsCnt, int* __restrict__ wsList) {
    __shared__ float gateT[NE * INL];   // 16 KB, [e][l]
    int tid = threadIdx.x;
    for (int i = 0; i < 16; ++i) {
        int f = tid + 256 * i;
        float v = gate_w[f];
        gateT[(f & 7) * INL + (f >> 3)] = v;
    }
    __syncthreads();

    int w = tid >> 6, lane = tid & 63;
    int tbase = blockIdx.x * 16 + w * 4;

    for (int tt = 0; tt < 4; ++tt) {
        int t = tbase + tt;
        float2 xv[4];
        for (int i = 0; i < 4; ++i)
            xv[i] = *(const float2*)(x + (size_t)t * INL + 2 * lane + 128 * i);

        float acc[NE];
        for (int e = 0; e < NE; ++e) acc[e] = 0.f;
        for (int i = 0; i < 4; ++i) {
            int c = 2 * lane + 128 * i;
            for (int e = 0; e < NE; ++e)
                acc[e] += xv[i].x * gateT[e * INL + c] + xv[i].y * gateT[e * INL + c + 1];
        }
        for (int e = 0; e < NE; ++e) {
            float a = acc[e];
            for (int off = 32; off >= 1; off >>= 1) a += __shfl_xor(a, off, 64);
            acc[e] = a;
        }
        float logit[NE];
        for (int e = 0; e < NE; ++e) logit[e] = acc[e] + wsRgam[e];

        int i0 = 0; float m0 = logit[0];
        for (int e = 1; e < NE; ++e) if (logit[e] > m0) { m0 = logit[e]; i0 = e; }
        int i1 = -1; float m1 = -3.4e38f;
        for (int e = 0; e < NE; ++e) if (e != i0 && logit[e] > m1) { m1 = logit[e]; i1 = e; }

        float S = 0.f;
        for (int e = 0; e < NE; ++e) S += expf(logit[e] - m0);
        float rw0 = 1.0f / S;
        float rw1 = expf(m1 - m0) / S;

        if (lane == 0) {
            selE[t] = i0 | (i1 << 8);
            selW[t] = make_float4(rw0 * wsGam[i0], rw1 * wsGam[i1], rw0, rw1);
            // scatter into per-(slot,expert) token lists
            int p0 = atomicAdd(wsCnt + i0 * 16, 1);
            wsList[i0 * N_TOK + p0] = t;
            int p1 = atomicAdd(wsCnt + (8 + i1) * 16, 1);
            wsList[(8 + i1) * N_TOK + p1] = t;
        }
    }
}

// ================= K3: top-2 sorted gather GEMM (two ordered passes) =======
// PASS 0: slot-0 lists. Every token appears exactly once -> epilogue WRITES
//         out = comb + rw0*bet_eff[e0] + rw1*bet_eff[e1]   (race-free init)
// PASS 1: slot-1 lists. Epilogue does plain out += comb (kernel-boundary
//         ordering guarantees pass-0 visibility; one writer per token row).
// K-loop is the proven r8 swizzle structure (0 LDS bank conflicts), but
// 1 expert x 8 kc steps per block instead of 8x8 -> 4x less MFMA work.
template<int PASS>
__global__ __launch_bounds__(256, 4)
void k_gemm2(const float* __restrict__ x, const ushort_t* __restrict__ wt,
             const int* __restrict__ wsCnt, const int* __restrict__ wsList,
             const int* __restrict__ selE, const float4* __restrict__ selW,
             const float* __restrict__ wsBet, float* __restrict__ out) {
    int bx = blockIdx.x;
    int ct = bx & 7;                   // col slab: ct*64..+64
    int bt = bx >> 3;                  // global row-tile index

    // map bt -> (expert e, local tile lt) via 8-entry prefix scan
    int e = -1, lt = 0, cntE = 0, run = 0;
    #pragma unroll
    for (int i = 0; i < 8; ++i) {
        int ci = wsCnt[(PASS * 8 + i) * 16];
        int ti = (ci + 63) >> 6;
        if (e < 0 && bt < run + ti) { e = i; lt = bt - run; cntE = ci; }
        run += ti;
    }
    if (e < 0) return;                 // surplus block
    const int* listE = wsList + (PASS * 8 + e) * N_TOK;

    __shared__ ushort_t Blds[2][64 * 64];   // 2 x 8 KB, swizzled [col][slot]

    int tid = threadIdx.x;
    int wid = tid >> 6, lane = tid & 63;
    int wm = wid * 16;                 // wave's 16-row slice
    int mrow = lane & 15, laneq = lane >> 4, q8 = laneq * 8, qr = laneq * 4;

    // gathered A row + single combine weight for this lane's row
    int idx = lt * 64 + wm + mrow;
    int tok = 0; float w = 0.f;
    if (idx < cntE) {
        tok = listE[idx];
        float4 w4 = selW[tok];
        w = PASS ? w4.y : w4.x;        // rw*gam for this slot's expert
    }
    const float* arowp = x + (size_t)tok * INL + q8;

    // B staging: thread stages chunks c0=tid, c1=tid+256 (chunk = 8 k, 16 B)
    // chunk c -> col=c>>3, kslot=c&7, src kgrp=(kslot-col)&7  (rotate swizzle)
    int c0 = tid, c1 = tid + 256;
    int col0 = c0 >> 3, kg0 = ((c0 & 7) - col0) & 7;
    int col1 = c1 >> 3, kg1 = ((c1 & 7) - col1) & 7;
    const ushort_t* pB0 = wt + (size_t)e * EOFF + (size_t)(ct * 64 + col0) * INL + kg0 * 8;
    const ushort_t* pB1 = wt + (size_t)e * EOFF + (size_t)(ct * 64 + col1) * INL + kg1 * 8;
    ushort_t* ldsW0 = &Blds[0][0] + (wid * 64) * 8;        // + buf*4096
    ushort_t* ldsW1 = &Blds[0][0] + (256 + wid * 64) * 8;

    // fragment read swizzle
    int fcol[4], frot0[4];
    for (int nt = 0; nt < 4; ++nt) {
        fcol[nt] = nt * 16 + mrow;
        frot0[nt] = (laneq + fcol[nt]) & 7;
    }

    floatx4 comb[4];
    for (int nt = 0; nt < 4; ++nt) comb[nt] = (floatx4){0.f, 0.f, 0.f, 0.f};

    // prologue: DMA tile kc=0 into buf0, drain
    dma16(pB0, ldsW0);
    dma16(pB1, ldsW1);
    __syncthreads();

    float4 ar[2][2];   // [ks][half] fp32 A fragments for current kc

    #pragma unroll 1
    for (int kc = 0; kc < 8; ++kc) {
        for (int ks = 0; ks < 2; ++ks) {
            const float* p = arowp + kc * 64 + ks * 32;
            ar[ks][0] = *(const float4*)p;
            ar[ks][1] = *(const float4*)(p + 4);
        }

        int buf = kc & 1;
        // issue DMA for next kc into the other buffer (flies under compute)
        if (kc < 7) {
            size_t off = (size_t)(kc + 1) * 64;
            int nb = buf ^ 1;
            dma16(pB0 + off, ldsW0 + nb * 4096);
            dma16(pB1 + off, ldsW1 + nb * 4096);
        }

        const ushort_t* B = &Blds[buf][0];
        short8 bf[4][2];
        for (int nt = 0; nt < 4; ++nt) {
            int cb = fcol[nt] * 64;
            bf[nt][0] = *(const short8*)&B[cb + frot0[nt] * 8];
            bf[nt][1] = *(const short8*)&B[cb + ((frot0[nt] + 4) & 7) * 8];
        }
        for (int ks = 0; ks < 2; ++ks) {
            union { uint4 u; short8 s; } af;
            float4 a0 = ar[ks][0], a1 = ar[ks][1];
            af.u.x = pkbf(a0.x * w, a0.y * w);
            af.u.y = pkbf(a0.z * w, a0.w * w);
            af.u.z = pkbf(a1.x * w, a1.y * w);
            af.u.w = pkbf(a1.z * w, a1.w * w);
            for (int nt = 0; nt < 4; ++nt)
                comb[nt] = __builtin_amdgcn_mfma_f32_16x16x32_bf16(
                    af.s, bf[nt][ks], comb[nt], 0, 0, 0);
        }
        __syncthreads();   // drain next-DMA (overlapped) + release buf readers
    }

    // epilogue (masked to valid list entries)
    for (int ri = 0; ri < 4; ++ri) {
        int row = wm + qr + ri;
        int idx2 = lt * 64 + row;
        if (idx2 >= cntE) continue;
        int tok2 = listE[idx2];
        if (PASS == 0) {
            int es = selE[tok2];
            float4 w4 = selW[tok2];
            int e0 = es & 255, e1 = es >> 8;
            for (int nt = 0; nt < 4; ++nt) {
                int col = ct * 64 + nt * 16 + mrow;
                float bet = w4.z * wsBet[e0 * OUTL + col] + w4.w * wsBet[e1 * OUTL + col];
                out[(size_t)tok2 * OUTL + col] = comb[nt][ri] + bet;
            }
        } else {
            for (int nt = 0; nt < 4; ++nt) {
                int col = ct * 64 + nt * 16 + mrow;
                out[(size_t)tok2 * OUTL + col] += comb[nt][ri];
            }
        }
    }
}

extern "C" void kernel_launch(void* const* d_in, const int* in_sizes, int n_in,
                              void* d_out, int out_size, void* d_ws, size_t ws_size,
                              hipStream_t stream) {
    const float* x        = (const float*)d_in[0];
    const float* ins      = (const float*)d_in[1];
    const float* gate_w   = (const float*)d_in[2];
    const float* expert_w = (const float*)d_in[3];
    const float* expert_b = (const float*)d_in[4];
    const float* gamma_w  = (const float*)d_in[5];
    const float* beta_w   = (const float*)d_in[6];
    const float* rmod_w   = (const float*)d_in[7];
    float* out = (float*)d_out;

    char* ws = (char*)d_ws;
    int*      wsCnt  = (int*)(ws + WS_CNT);
    float*    wsGam  = (float*)(ws + WS_GAM);
    float*    wsRgam = (float*)(ws + WS_RGAM);
    float*    wsBet  = (float*)(ws + WS_BET);
    int*      selE   = (int*)(ws + WS_SELE);
    float4*   selW   = (float4*)(ws + WS_SELW);
    ushort_t* wt     = (ushort_t*)(ws + WS_WT);
    int*      wsList = (int*)(ws + WS_LIST);

    k_prep<<<641, 256, 0, stream>>>(ins, expert_w, expert_b,
                                    gamma_w, beta_w, rmod_w,
                                    wt, wsBet, wsGam, wsRgam, wsCnt);
    k_route<<<N_TOK / 16, 256, 0, stream>>>(x, gate_w, wsGam, wsRgam,
                                            selE, selW, wsCnt, wsList);
    k_gemm2<0><<<MAXT * 8, 256, 0, stream>>>(x, wt, wsCnt, wsList,
                                             selE, selW, wsBet, out);
    k_gemm2<1><<<MAXT * 8, 256, 0, stream>>>(x, wt, wsCnt, wsList,
                                             selE, selW, wsBet, out);
}